// Round 12
// baseline (361.110 us; speedup 1.0000x reference)
//
#include <hip/hip_runtime.h>
#include <hip/hip_bf16.h>
#include <math.h>

#define HID 2048
#define NH 16
#define NKV 8
#define HD 128
#define SEQ 2048
#define EPS 1e-6f
#define SCALE 0.08838834764831845f   // 128^-0.5
#define SCALE2 0.1275174481f         // SCALE * log2(e): softmax in base-2 domain

typedef __attribute__((ext_vector_type(8))) short bf8_t;   // 8 bf16 (4 VGPRs)
typedef __attribute__((ext_vector_type(4))) short sh4;     // 4 bf16 (2 VGPRs)
typedef __attribute__((ext_vector_type(4))) float f4_t;    // 4 fp32

__device__ __forceinline__ short f2bf(float f) {
    union { __hip_bfloat16 h; short s; } u;
    u.h = __float2bfloat16(f);
    return u.s;
}
__device__ __forceinline__ float bf2f(short s) {
    union { short s; __hip_bfloat16 h; } u;
    u.s = s;
    return __bfloat162float(u.h);
}
__device__ __forceinline__ bf8_t pack8(const float4& a, const float4& b) {
    bf8_t r;
    r[0] = f2bf(a.x); r[1] = f2bf(a.y); r[2] = f2bf(a.z); r[3] = f2bf(a.w);
    r[4] = f2bf(b.x); r[5] = f2bf(b.y); r[6] = f2bf(b.z); r[7] = f2bf(b.w);
    return r;
}
// async global->LDS DMA, 16 B per lane; lds dest = wave-uniform base + lane*16
__device__ __forceinline__ void gload16(const short* g, short* l) {
    __builtin_amdgcn_global_load_lds(
        (const __attribute__((address_space(1))) unsigned int*)g,
        (__attribute__((address_space(3))) unsigned int*)l, 16, 0, 0);
}

__device__ __forceinline__ float wave_reduce_sum(float v) {
#pragma unroll
    for (int off = 32; off > 0; off >>= 1) v += __shfl_xor(v, off);
    return v;
}

// ---------------- 1. fused prep: f2bf(w_qkv) | f2bf(w_o) | hidden RMSNorm ------
__global__ __launch_bounds__(256) void prep_kernel(
    const float* __restrict__ w_qkv, short* __restrict__ wqb,
    const float* __restrict__ w_o, short* __restrict__ wob,
    const float* __restrict__ x, const float* __restrict__ w,
    short* __restrict__ out) {
    int bid = blockIdx.x;
    int tid = threadIdx.x;
    if (bid < 4096) {
        int i = bid * 256 + tid;
        float4 a = *(const float4*)(w_qkv + (size_t)i * 8);
        float4 b = *(const float4*)(w_qkv + (size_t)i * 8 + 4);
        *(bf8_t*)(wqb + (size_t)i * 8) = pack8(a, b);
        return;
    }
    if (bid < 6144) {
        int i = (bid - 4096) * 256 + tid;
        float4 a = *(const float4*)(w_o + (size_t)i * 8);
        float4 b = *(const float4*)(w_o + (size_t)i * 8 + 4);
        *(bf8_t*)(wob + (size_t)i * 8) = pack8(a, b);
        return;
    }
    int row = bid - 6144;
    const float* xr = x + (size_t)row * HID;
    float4 a = *(const float4*)(xr + tid * 8);
    float4 b = *(const float4*)(xr + tid * 8 + 4);
    float ss = a.x * a.x + a.y * a.y + a.z * a.z + a.w * a.w +
               b.x * b.x + b.y * b.y + b.z * b.z + b.w * b.w;
    ss = wave_reduce_sum(ss);
    __shared__ float part[4];
    __shared__ float s_scale;
    if ((tid & 63) == 0) part[tid >> 6] = ss;
    __syncthreads();
    if (tid == 0) {
        float t = part[0] + part[1] + part[2] + part[3];
        s_scale = rsqrtf(t / (float)HID + EPS);
    }
    __syncthreads();
    float sc = s_scale;
    float4 wa = *(const float4*)(w + tid * 8);
    float4 wb = *(const float4*)(w + tid * 8 + 4);
    float4 oa = make_float4(a.x * sc * wa.x, a.y * sc * wa.y,
                            a.z * sc * wa.z, a.w * sc * wa.w);
    float4 ob = make_float4(b.x * sc * wb.x, b.y * sc * wb.y,
                            b.z * sc * wb.z, b.w * sc * wb.w);
    *(bf8_t*)(out + (size_t)row * HID + tid * 8) = pack8(oa, ob);
}

// ---------------- 2. bf16 MFMA GEMM 128x128: C = A @ B^T, BK=64 (qkv) ----------
template <int MODE>
__global__ __launch_bounds__(256) void gemm_mfma_kernel(
    const short* __restrict__ A, const short* __restrict__ B,
    float* __restrict__ Cf, short* __restrict__ Q, short* __restrict__ Kp,
    short* __restrict__ Vr, int M, int N, int K) {
    __shared__ short As[128][64];
    __shared__ short Bs[128][64];
    int tid = threadIdx.x;
    int wv = tid >> 6, lane = tid & 63;
    int n16 = lane & 15, qd = lane >> 4;
    int m0 = blockIdx.y * 128, n0 = blockIdx.x * 128;
    int wm = (wv >> 1) * 64, wn = (wv & 1) * 64;
    int sr8 = lane >> 3, slot = lane & 7;

    size_t ainv[4], binv[4];
#pragma unroll
    for (int it = 0; it < 4; ++it) {
        int row = wv * 32 + it * 8 + sr8;
        int chunk = (slot - row) & 7;
        ainv[it] = (size_t)(m0 + row) * K + chunk * 8;
        binv[it] = (size_t)(n0 + row) * K + chunk * 8;
    }

    f4_t acc[4][4];
#pragma unroll
    for (int i = 0; i < 4; ++i)
#pragma unroll
        for (int j = 0; j < 4; ++j) acc[i][j] = (f4_t){0.f, 0.f, 0.f, 0.f};

    for (int k0 = 0; k0 < K; k0 += 64) {
        __syncthreads();
#pragma unroll
        for (int it = 0; it < 4; ++it) {
            gload16(A + ainv[it] + k0, &As[wv * 32 + it * 8][0]);
            gload16(B + binv[it] + k0, &Bs[wv * 32 + it * 8][0]);
        }
        __syncthreads();

        bf8_t af[4][2], bf[4][2];
#pragma unroll
        for (int t = 0; t < 4; ++t)
#pragma unroll
            for (int ks = 0; ks < 2; ++ks) {
                int ar = wm + t * 16 + n16;
                af[t][ks] = *(const bf8_t*)&As[ar][(((ks * 4 + qd) + ar) & 7) * 8];
                int br = wn + t * 16 + n16;
                bf[t][ks] = *(const bf8_t*)&Bs[br][(((ks * 4 + qd) + br) & 7) * 8];
            }
#pragma unroll
        for (int ks = 0; ks < 2; ++ks)
#pragma unroll
            for (int mt = 0; mt < 4; ++mt)
#pragma unroll
                for (int nt = 0; nt < 4; ++nt)
                    acc[mt][nt] = __builtin_amdgcn_mfma_f32_16x16x32_bf16(
                        af[mt][ks], bf[nt][ks], acc[mt][nt], 0, 0, 0);
    }

#pragma unroll
    for (int mt = 0; mt < 4; ++mt)
#pragma unroll
        for (int nt = 0; nt < 4; ++nt)
#pragma unroll
            for (int r = 0; r < 4; ++r) {
                int gm = m0 + wm + mt * 16 + qd * 4 + r;
                int gn = n0 + wn + nt * 16 + n16;
                float v = acc[mt][nt][r];
                if (MODE == 0) {
                    Cf[(size_t)gm * N + gn] = v;
                } else {
                    if (gn < NH * HD)
                        Q[(size_t)gm * (NH * HD) + gn] = f2bf(v);
                    else if (gn < (NH + NKV) * HD)
                        Kp[(size_t)gm * (NKV * HD) + (gn - NH * HD)] = f2bf(v);
                    else
                        Vr[(size_t)gm * (NKV * HD) + (gn - (NH + NKV) * HD)] = f2bf(v);
                }
            }
}

// ---------------- 2b. bf16 MFMA GEMM 128x64 tiles (out-proj; 512 blocks) -------
__global__ __launch_bounds__(256) void gemm2_mfma_kernel(
    const short* __restrict__ A, const short* __restrict__ B,
    float* __restrict__ Cf, int M, int N, int K) {
    __shared__ short As[128][64];
    __shared__ short Bs[64][64];
    int tid = threadIdx.x;
    int wv = tid >> 6, lane = tid & 63;
    int n16 = lane & 15, qd = lane >> 4;
    int m0 = blockIdx.y * 128, n0 = blockIdx.x * 64;
    int wm = (wv >> 1) * 64, wn = (wv & 1) * 32;
    int sr8 = lane >> 3, slot = lane & 7;

    size_t ainv[4], binv[2];
#pragma unroll
    for (int it = 0; it < 4; ++it) {
        int row = wv * 32 + it * 8 + sr8;
        int chunk = (slot - row) & 7;
        ainv[it] = (size_t)(m0 + row) * K + chunk * 8;
    }
#pragma unroll
    for (int it = 0; it < 2; ++it) {
        int row = wv * 16 + it * 8 + sr8;
        int chunk = (slot - row) & 7;
        binv[it] = (size_t)(n0 + row) * K + chunk * 8;
    }

    f4_t acc[4][2];
#pragma unroll
    for (int i = 0; i < 4; ++i)
#pragma unroll
        for (int j = 0; j < 2; ++j) acc[i][j] = (f4_t){0.f, 0.f, 0.f, 0.f};

    for (int k0 = 0; k0 < K; k0 += 64) {
        __syncthreads();
#pragma unroll
        for (int it = 0; it < 4; ++it)
            gload16(A + ainv[it] + k0, &As[wv * 32 + it * 8][0]);
#pragma unroll
        for (int it = 0; it < 2; ++it)
            gload16(B + binv[it] + k0, &Bs[wv * 16 + it * 8][0]);
        __syncthreads();

        bf8_t af[4][2], bf[2][2];
#pragma unroll
        for (int t = 0; t < 4; ++t)
#pragma unroll
            for (int ks = 0; ks < 2; ++ks) {
                int ar = wm + t * 16 + n16;
                af[t][ks] = *(const bf8_t*)&As[ar][(((ks * 4 + qd) + ar) & 7) * 8];
            }
#pragma unroll
        for (int t = 0; t < 2; ++t)
#pragma unroll
            for (int ks = 0; ks < 2; ++ks) {
                int br = wn + t * 16 + n16;
                bf[t][ks] = *(const bf8_t*)&Bs[br][(((ks * 4 + qd) + br) & 7) * 8];
            }
#pragma unroll
        for (int ks = 0; ks < 2; ++ks)
#pragma unroll
            for (int mt = 0; mt < 4; ++mt)
#pragma unroll
                for (int nt = 0; nt < 2; ++nt)
                    acc[mt][nt] = __builtin_amdgcn_mfma_f32_16x16x32_bf16(
                        af[mt][ks], bf[nt][ks], acc[mt][nt], 0, 0, 0);
    }

#pragma unroll
    for (int mt = 0; mt < 4; ++mt)
#pragma unroll
        for (int nt = 0; nt < 2; ++nt)
#pragma unroll
            for (int r = 0; r < 4; ++r) {
                int gm = m0 + wm + mt * 16 + qd * 4 + r;
                int gn = n0 + wn + nt * 16 + n16;
                Cf[(size_t)gm * N + gn] = acc[mt][nt][r];
            }
}

// ---------------- 3. fused mid: V transpose | q/k RMSNorm + RoPE ----------------
__global__ __launch_bounds__(256) void mid_kernel(
    const short* __restrict__ vr, short* __restrict__ vt,
    short* __restrict__ q, short* __restrict__ k,
    const float* __restrict__ qw, const float* __restrict__ kw,
    const int* __restrict__ pos) {
    int bid = blockIdx.x;
    int tid = threadIdx.x;
    if (bid < 512) {  // ---- V transpose, 64x64 tile ----
        __shared__ short t[64][64];
        int s0 = (bid & 31) * 64, d0 = (bid >> 5) * 64;
        int sl = tid >> 3, ch = tid & 7;
#pragma unroll
        for (int it = 0; it < 2; ++it) {
            int s_local = it * 32 + sl;
            bf8_t vv = *(const bf8_t*)(vr + (size_t)(s0 + s_local) * (NKV * HD) + d0 + ch * 8);
            *(bf8_t*)&t[s_local][((ch + s_local) & 7) * 8] = vv;
        }
        __syncthreads();
#pragma unroll
        for (int it = 0; it < 2; ++it) {
            int d_local = it * 32 + sl;
            int sbase = ch * 8;
            bf8_t o;
#pragma unroll
            for (int j = 0; j < 8; ++j) {
                int s = sbase + j;
                o[j] = t[s][(((d_local >> 3) + s) & 7) * 8 + (d_local & 7)];
            }
            *(bf8_t*)(vt + (size_t)(d0 + d_local) * SEQ + s0 + sbase) = o;
        }
        return;
    }
    // ---- q/k RMSNorm + RoPE: two 128-thread units per block ----
    int u = (bid - 512) * 2 + (tid >> 7);
    int ui = tid >> 7, d = tid & 127;
    int s = u / 24, hh = u % 24;
    short* ptr;
    const float* w;
    if (hh < NH) {
        ptr = q + (size_t)s * (NH * HD) + hh * HD;
        w = qw;
    } else {
        ptr = k + (size_t)s * (NKV * HD) + (hh - NH) * HD;
        w = kw;
    }
    float x = bf2f(ptr[d]);
    float ss = wave_reduce_sum(x * x);
    __shared__ float part[2][2];
    if ((d & 63) == 0) part[ui][d >> 6] = ss;
    __syncthreads();
    float tot = part[ui][0] + part[ui][1];
    float xn = x * rsqrtf(tot / (float)HD + EPS) * w[d];
    __shared__ float sh[2][HD];
    sh[ui][d] = xn;
    __syncthreads();
    int j = d & 63;
    float inv = __expf((float)j * -0.14391156831f);  // 10000^(-j/64)
    float fr = (float)pos[s] * inv;
    float sn, cs;
    __sincosf(fr, &sn, &cs);
    float o;
    if (d < 64)
        o = xn * cs - sh[ui][d + 64] * sn;
    else
        o = xn * cs + sh[ui][d - 64] * sn;
    ptr[d] = f2bf(o);
}

// ---------------- 4. MFMA flash attention v9 ----------------
// 48 equal chunks/head (5-6 k-tiles) -> 768 blocks = exactly 3/CU at 40 KB LDS
// (12 waves/CU). Single LDS K/V buffer; next tile prefetched into VGPRs during
// compute, ds_write'd between barriers (global latency off critical path).
// Softmax in base-2 domain (exp2f = bare v_exp). 61 pieces/head, table-merged.
__constant__ unsigned char c_c0[16] =
    {0,0,1,2,3,5,7,10,12,16,19,23,27,32,37,42};
__constant__ unsigned char c_pbase[17] =
    {0,1,3,5,7,10,13,16,19,23,27,32,37,43,49,55,61};

__device__ __forceinline__ short* part_ptr(short* opA, short* opB, short* opC, int pb) {
    if (pb < 512) return opA + (size_t)pb * 16384;
    if (pb < 896) return opB + (size_t)(pb - 512) * 16384;
    return opC + (size_t)(pb - 896) * 16384;
}

struct Pref { bf8_t kr[4]; bf8_t vr[4]; };

__device__ __forceinline__ void pref_load(
    Pref& p, const short* __restrict__ k, const short* __restrict__ vt,
    int t0, int kvh, int wv, int lane) {
#pragma unroll
    for (int it = 0; it < 4; ++it) {
        int krow = wv * 16 + it * 4 + (lane >> 4);
        int kch = lane & 15;
        p.kr[it] = *(const bf8_t*)(k + (size_t)(t0 + krow) * (NKV * HD) + kvh * HD + kch * 8);
        int vdim = wv * 32 + it * 8 + (lane >> 3);
        int vch = lane & 7;
        p.vr[it] = *(const bf8_t*)(vt + (size_t)(kvh * HD + vdim) * SEQ + t0 + vch * 8);
    }
}
__device__ __forceinline__ void pref_store(
    const Pref& p, short (&kb)[64][128], short (&vb)[128][64], int wv, int lane) {
#pragma unroll
    for (int it = 0; it < 4; ++it) {
        int krow = wv * 16 + it * 4 + (lane >> 4);
        int kch = lane & 15;
        *(bf8_t*)&kb[krow][((kch + krow) & 15) * 8] = p.kr[it];
        int vdim = wv * 32 + it * 8 + (lane >> 3);
        int vch = lane & 7;
        *(bf8_t*)&vb[vdim][((vch + vdim) & 7) * 8] = p.vr[it];
    }
}

__device__ __forceinline__ void load_q(
    bf8_t (&qf)[2][4], const short* __restrict__ q,
    int qt, int h, int wv, int n, int qd) {
#pragma unroll
    for (int rg = 0; rg < 2; ++rg) {
        const short* qp =
            q + (size_t)(qt * 128 + wv * 32 + rg * 16 + n) * (NH * HD) + h * HD + qd * 8;
#pragma unroll
        for (int ks = 0; ks < 4; ++ks) qf[rg][ks] = *(const bf8_t*)(qp + ks * 32);
    }
}

__device__ __forceinline__ void attn_tile(
    const short (&kb)[64][128], const short (&vb)[128][64],
    short (&psh)[4][16][64],
    const bf8_t (&qf)[2][4], f4_t (&of)[2][8],
    float (&m_i)[2][4], float (&l_p)[2][4],
    int wv, int n, int qd, int koff) {
    f4_t sc[2][4];
#pragma unroll
    for (int rg = 0; rg < 2; ++rg)
#pragma unroll
        for (int kk = 0; kk < 4; ++kk) sc[rg][kk] = (f4_t){0.f, 0.f, 0.f, 0.f};
#pragma unroll
    for (int kk = 0; kk < 4; ++kk) {
        int key = kk * 16 + n;
#pragma unroll
        for (int ks = 0; ks < 4; ++ks) {
            bf8_t kf = *(const bf8_t*)&kb[key][(((ks * 4 + qd) + key) & 15) * 8];
            sc[0][kk] = __builtin_amdgcn_mfma_f32_16x16x32_bf16(qf[0][ks], kf, sc[0][kk], 0, 0, 0);
            sc[1][kk] = __builtin_amdgcn_mfma_f32_16x16x32_bf16(qf[1][ks], kf, sc[1][kk], 0, 0, 0);
        }
    }
    bf8_t pf[2][2];
#pragma unroll
    for (int rg = 0; rg < 2; ++rg) {
        int rows0 = wv * 32 + rg * 16;
        bool needm = (koff + 63 > rows0);  // wave-uniform
#pragma unroll
        for (int kk = 0; kk < 4; ++kk)
#pragma unroll
            for (int r = 0; r < 4; ++r) {
                float s = sc[rg][kk][r] * SCALE2;   // base-2 domain
                if (needm && (koff + kk * 16 + n > rows0 + qd * 4 + r)) s = -1e30f;
                sc[rg][kk][r] = s;
            }
#pragma unroll
        for (int r = 0; r < 4; ++r) {
            float mx = fmaxf(fmaxf(sc[rg][0][r], sc[rg][1][r]),
                             fmaxf(sc[rg][2][r], sc[rg][3][r]));
#pragma unroll
            for (int off = 1; off < 16; off <<= 1) mx = fmaxf(mx, __shfl_xor(mx, off));
            float mnew = fmaxf(m_i[rg][r], mx);
            float al = exp2f(m_i[rg][r] - mnew);
            m_i[rg][r] = mnew;
            float lsum = 0.f;
            int row = qd * 4 + r;
#pragma unroll
            for (int kk = 0; kk < 4; ++kk) {
                float p = exp2f(sc[rg][kk][r] - mnew);
                psh[wv][row][((kk * 16 + n) + row * 8) & 63] = f2bf(p);
                lsum += p;
            }
            l_p[rg][r] = l_p[rg][r] * al + lsum;
#pragma unroll
            for (int nb = 0; nb < 8; ++nb) of[rg][nb][r] *= al;
        }
        __builtin_amdgcn_wave_barrier();  // psh writes before reads (in-order LDS)
#pragma unroll
        for (int ks2 = 0; ks2 < 2; ++ks2)
            pf[rg][ks2] = *(const bf8_t*)&psh[wv][n][((ks2 * 32 + qd * 8) + n * 8) & 63];
        __builtin_amdgcn_wave_barrier();  // reads before next group's overwrite
    }
#pragma unroll
    for (int ks2 = 0; ks2 < 2; ++ks2)
#pragma unroll
        for (int nb = 0; nb < 8; ++nb) {
            int dim = nb * 16 + n;
            bf8_t vf = *(const bf8_t*)&vb[dim][(((ks2 * 4 + qd) + dim) & 7) * 8];
            of[0][nb] = __builtin_amdgcn_mfma_f32_16x16x32_bf16(pf[0][ks2], vf, of[0][nb], 0, 0, 0);
            of[1][nb] = __builtin_amdgcn_mfma_f32_16x16x32_bf16(pf[1][ks2], vf, of[1][nb], 0, 0, 0);
        }
}

__device__ __forceinline__ void flush_piece(
    short* opA, short* opB, short* opC, float* ml, int slot,
    f4_t (&of)[2][8], float (&m_i)[2][4], float (&l_p)[2][4],
    int wv, int lane, int n, int qd) {
    float lred[2][4];
#pragma unroll
    for (int rg = 0; rg < 2; ++rg)
#pragma unroll
        for (int r = 0; r < 4; ++r) {
            float lr = l_p[rg][r];
#pragma unroll
            for (int off = 1; off < 16; off <<= 1) lr += __shfl_xor(lr, off);
            lred[rg][r] = lr;
        }
    short* op = part_ptr(opA, opB, opC, slot);
#pragma unroll
    for (int rg = 0; rg < 2; ++rg)
#pragma unroll
        for (int nb = 0; nb < 8; ++nb) {
            sh4 pk;
#pragma unroll
            for (int r = 0; r < 4; ++r) pk[r] = f2bf(of[rg][nb][r]);
            *(sh4*)(op + ((size_t)((wv * 2 + rg) * 8 + nb) * 64 + lane) * 4) = pk;
        }
    if (n == 0) {
#pragma unroll
        for (int rg = 0; rg < 2; ++rg)
#pragma unroll
            for (int r = 0; r < 4; ++r) {
                int rl = wv * 32 + rg * 16 + qd * 4 + r;
                ml[(size_t)slot * 256 + rl * 2] = m_i[rg][r];
                ml[(size_t)slot * 256 + rl * 2 + 1] = lred[rg][r];
            }
    }
}

__device__ __forceinline__ void adv(int& aqt, int& akt) {
    if (++akt == 2 * (aqt + 1)) { akt = 0; ++aqt; }
}

__global__ __launch_bounds__(256, 3) void attn_chunk_kernel(
    const short* __restrict__ q, const short* __restrict__ k,
    const short* __restrict__ vt, short* __restrict__ opA,
    short* __restrict__ opB, short* __restrict__ opC,
    float* __restrict__ ml) {
    __shared__ short kbuf[64][128];   // 16 KB
    __shared__ short vbuf[128][64];   // 16 KB
    __shared__ short psh[4][16][64];  // 8 KB -> 40 KB, 3 blocks/CU

    int tid = threadIdx.x;
    int wv = tid >> 6, lane = tid & 63;
    int n = lane & 15, qd = lane >> 4;

    int bid = blockIdx.x;            // 768 blocks; bid&7 = kv-head (XCD grouping)
    int kvh = bid & 7;
    int rest = bid >> 3;             // 0..95
    int h = kvh * 2 + (rest & 1);
    int c = rest >> 1;               // chunk 0..47
    int s = (17 * c) / 3;
    int e = (17 * (c + 1)) / 3;      // 5 or 6 tiles

    int qt = 0;
    while ((qt + 1) * (qt + 2) <= s) qt++;
    int kt = s - qt * (qt + 1);

    bf8_t qf[2][4];
    load_q(qf, q, qt, h, wv, n, qd);

    f4_t of[2][8];
#pragma unroll
    for (int rg = 0; rg < 2; ++rg)
#pragma unroll
        for (int x = 0; x < 8; ++x) of[rg][x] = (f4_t){0.f, 0.f, 0.f, 0.f};
    float m_i[2][4] = {{-1e30f, -1e30f, -1e30f, -1e30f},
                       {-1e30f, -1e30f, -1e30f, -1e30f}};
    float l_p[2][4] = {{0.f, 0.f, 0.f, 0.f}, {0.f, 0.f, 0.f, 0.f}};

    // prologue: LDS <- tile s; prefetch regs <- tile s+1
    Pref pr;
    pref_load(pr, k, vt, kt * 64, kvh, wv, lane);
    pref_store(pr, kbuf, vbuf, wv, lane);
    int pqt = qt, pkt = kt;
    adv(pqt, pkt);
    if (s + 1 < e) pref_load(pr, k, vt, pkt * 64, kvh, wv, lane);
    __syncthreads();

    for (int g = s; g < e; ++g) {
        bool last = (g + 1 == e);
        bool segLast = (kt == 2 * qt + 1);
        attn_tile(kbuf, vbuf, psh, qf, of, m_i, l_p, wv, n, qd, kt * 64 - qt * 128);
        if (!last) {
            __syncthreads();                 // all waves off old tile
            pref_store(pr, kbuf, vbuf, wv, lane);  // tile g+1 (waits vmcnt)
            if (g + 2 < e) {
                adv(pqt, pkt);
                pref_load(pr, k, vt, pkt * 64, kvh, wv, lane);  // tile g+2
            }
            __syncthreads();                 // tile g+1 visible
        }
        if (segLast || last) {
            int slot = h * 61 + c_pbase[qt] + (c - c_c0[qt]);
            flush_piece(opA, opB, opC, ml, slot, of, m_i, l_p, wv, lane, n, qd);
            if (!last) {
                qt += 1; kt = 0;
                load_q(qf, q, qt, h, wv, n, qd);
#pragma unroll
                for (int rg = 0; rg < 2; ++rg)
#pragma unroll
                    for (int x = 0; x < 8; ++x) of[rg][x] = (f4_t){0.f, 0.f, 0.f, 0.f};
#pragma unroll
                for (int rg = 0; rg < 2; ++rg)
#pragma unroll
                    for (int r = 0; r < 4; ++r) { m_i[rg][r] = -1e30f; l_p[rg][r] = 0.f; }
            }
        } else {
            kt += 1;
        }
    }
}

// ---------------- 4b. merge pieces per q-tile (table-driven, base-2) ----------
__global__ __launch_bounds__(256) void attn_merge_kernel(
    const short* __restrict__ opA, const short* __restrict__ opB,
    const short* __restrict__ opC, const float* __restrict__ ml,
    short* __restrict__ o) {
    int bid = blockIdx.x;             // 256: h*16 + qt
    int h = bid >> 4, qt = bid & 15;
    int base = h * 61 + c_pbase[qt];
    int cnt = c_pbase[qt + 1] - c_pbase[qt];
    int tid = threadIdx.x;
    int wv = tid >> 6, lane = tid & 63;
    int n = lane & 15, qd = lane >> 4;
#pragma unroll
    for (int rg = 0; rg < 2; ++rg) {
        int rl0 = wv * 32 + rg * 16 + qd * 4;
        float M[4], L[4], invL[4];
#pragma unroll
        for (int r = 0; r < 4; ++r) { M[r] = -1e30f; L[r] = 0.f; }
        for (int cc = 0; cc < cnt; ++cc)
#pragma unroll
            for (int r = 0; r < 4; ++r)
                M[r] = fmaxf(M[r], ml[(size_t)(base + cc) * 256 + (rl0 + r) * 2]);
        for (int cc = 0; cc < cnt; ++cc)
#pragma unroll
            for (int r = 0; r < 4; ++r) {
                float wc = exp2f(ml[(size_t)(base + cc) * 256 + (rl0 + r) * 2] - M[r]);
                L[r] += wc * ml[(size_t)(base + cc) * 256 + (rl0 + r) * 2 + 1];
            }
#pragma unroll
        for (int r = 0; r < 4; ++r) invL[r] = 1.0f / L[r];

        float acc[8][4];
#pragma unroll
        for (int nb = 0; nb < 8; ++nb)
#pragma unroll
            for (int r = 0; r < 4; ++r) acc[nb][r] = 0.f;
        for (int cc = 0; cc < cnt; ++cc) {
            const short* op = part_ptr((short*)opA, (short*)opB, (short*)opC, base + cc);
            float wc[4];
#pragma unroll
            for (int r = 0; r < 4; ++r)
                wc[r] = exp2f(ml[(size_t)(base + cc) * 256 + (rl0 + r) * 2] - M[r]);
#pragma unroll
            for (int nb = 0; nb < 8; ++nb) {
                sh4 pk = *(const sh4*)(op + ((size_t)((wv * 2 + rg) * 8 + nb) * 64 + lane) * 4);
#pragma unroll
                for (int r = 0; r < 4; ++r) acc[nb][r] += wc[r] * bf2f(pk[r]);
            }
        }
#pragma unroll
        for (int nb = 0; nb < 8; ++nb)
#pragma unroll
            for (int r = 0; r < 4; ++r) {
                int row = qt * 128 + rl0 + r;
                o[(size_t)row * (NH * HD) + h * HD + nb * 16 + n] =
                    f2bf(acc[nb][r] * invL[r]);
            }
    }
}

// ---------------- launch ----------------
extern "C" void kernel_launch(void* const* d_in, const int* in_sizes, int n_in,
                              void* d_out, int out_size, void* d_ws, size_t ws_size,
                              hipStream_t stream) {
    const int* positions   = (const int*)d_in[0];
    const float* hidden    = (const float*)d_in[1];
    const float* ln_w      = (const float*)d_in[2];
    const float* w_qkv     = (const float*)d_in[3];
    const float* w_o       = (const float*)d_in[4];
    const float* q_norm_w  = (const float*)d_in[5];
    const float* k_norm_w  = (const float*)d_in[6];
    float* out = (float*)d_out;

    char* base = (char*)d_ws;
    short* hnb   = (short*)(base);                        // 8 MB: hn bf16 -> attn-out bf16
    short* wqb   = (short*)(base + ((size_t)8 << 20));    // 16 MB: w_qkv bf16 (dead after gemm1)
    short* vtb   = (short*)(base + ((size_t)8 << 20));    // 4 MB: v^T (dead wqb region)
    short* opB   = (short*)(base + ((size_t)12 << 20));   // 12 MB: pieces 512..895
    short* wob   = (short*)(base + ((size_t)24 << 20));   // 8 MB: w_o bf16
    short* qbf   = (short*)(base + ((size_t)32 << 20));   // 8 MB: q bf16
    short* kbf   = (short*)(base + ((size_t)40 << 20));   // 4 MB: k bf16
    short* vrow  = (short*)(base + ((size_t)44 << 20));   // 4 MB: v row-major (dead after mid)
    short* opC   = (short*)(base + ((size_t)44 << 20));   // 2.5 MB: pieces 896..975
    float* mlbuf = (float*)(base + ((size_t)47 << 20));   // ~1 MB: m/l
    short* opA   = (short*)d_out;                         // 16 MB: pieces 0..511

    prep_kernel<<<8192, 256, 0, stream>>>(w_qkv, wqb, w_o, wob, hidden, ln_w, hnb);
    gemm_mfma_kernel<1><<<dim3(32, 16), 256, 0, stream>>>(
        hnb, wqb, nullptr, qbf, kbf, vrow, SEQ, (NH + 2 * NKV) * HD, HID);
    mid_kernel<<<512 + 24576, 256, 0, stream>>>(
        vrow, vtb, qbf, kbf, q_norm_w, k_norm_w, positions);
    attn_chunk_kernel<<<768, 256, 0, stream>>>(qbf, kbf, vtb, opA, opB, opC, mlbuf);
    attn_merge_kernel<<<256, 256, 0, stream>>>(opA, opB, opC, mlbuf, hnb);
    gemm2_mfma_kernel<<<dim3(32, 16), 256, 0, stream>>>(
        hnb, wob, out, SEQ, NH * HD, HID);
}